// Round 6
// baseline (308.724 us; speedup 1.0000x reference)
//
#include <hip/hip_runtime.h>
#include <hip/hip_bf16.h>

// ---------------------------------------------------------------------------
// EnhancedTernaryLinear: out = (x @ W^T) * scale + bias
// M=8192, N=4096, K=4096. x->bf16, W(ternary)->bf16, then 256x256 MFMA GEMM.
// R6: occupancy restructure. 1024 threads = 16 waves of 64x64 wave-tiles
// (acc=64 AGPR, total <=128 regs => 4 waves/SIMD), BK=32, 64 KiB LDS dbuf.
// Per tile: stage(T+1) | rd aF | LGKM(3/2/1/0)-interleaved 4x MFMA rows |
// VMW(0) | barrier | read-ahead bF(T+1) | last MFMA row. 1 barrier/tile.
// ---------------------------------------------------------------------------

#define M_DIM 8192
#define N_DIM 4096
#define K_DIM 4096
#define BK 32
#define NT (K_DIM / BK)   // 128 K-tiles

typedef __attribute__((ext_vector_type(8))) short bf16x8;
typedef __attribute__((ext_vector_type(4))) float f32x4;

__device__ __forceinline__ unsigned short f2bf(float f) {
  unsigned int u = __float_as_uint(f);
  unsigned int r = (u + 0x7FFFu + ((u >> 16) & 1u)) >> 16;
  return (unsigned short)r;
}

__device__ __forceinline__ void async16(const void* g, void* l) {
  __builtin_amdgcn_global_load_lds(
      (const __attribute__((address_space(1))) void*)g,
      (__attribute__((address_space(3))) void*)l, 16, 0, 0);
}

// ---------------- conversion kernels ----------------

__global__ void cvt_x_kernel(const float* __restrict__ x,
                             unsigned short* __restrict__ xb, long n) {
  long i0 = ((long)blockIdx.x * blockDim.x + threadIdx.x) * 8;
  long stride = (long)gridDim.x * blockDim.x * 8;
  for (long i = i0; i < n; i += stride) {
    float4 v0 = *(const float4*)(x + i);
    float4 v1 = *(const float4*)(x + i + 4);
    bf16x8 o;
    o[0] = (short)f2bf(v0.x); o[1] = (short)f2bf(v0.y);
    o[2] = (short)f2bf(v0.z); o[3] = (short)f2bf(v0.w);
    o[4] = (short)f2bf(v1.x); o[5] = (short)f2bf(v1.y);
    o[6] = (short)f2bf(v1.z); o[7] = (short)f2bf(v1.w);
    *(bf16x8*)(xb + i) = o;
  }
}

__device__ __forceinline__ unsigned short i2bf(int v) {
  return v == 0 ? (unsigned short)0
                : (v > 0 ? (unsigned short)0x3F80 : (unsigned short)0xBF80);
}

__global__ void cvt_w_kernel(const int* __restrict__ w,
                             unsigned short* __restrict__ wb, long n) {
  long i0 = ((long)blockIdx.x * blockDim.x + threadIdx.x) * 8;
  long stride = (long)gridDim.x * blockDim.x * 8;
  for (long i = i0; i < n; i += stride) {
    int4 a = *(const int4*)(w + i);
    int4 b = *(const int4*)(w + i + 4);
    bf16x8 o;
    o[0] = (short)i2bf(a.x); o[1] = (short)i2bf(a.y);
    o[2] = (short)i2bf(a.z); o[3] = (short)i2bf(a.w);
    o[4] = (short)i2bf(b.x); o[5] = (short)i2bf(b.y);
    o[6] = (short)i2bf(b.z); o[7] = (short)i2bf(b.w);
    *(bf16x8*)(wb + i) = o;
  }
}

// ---------------- 256x256 GEMM, 16 waves, BK=32, 64 KiB LDS ----------------
// LDS layout (bytes): buf b at b*32768: A region [256 rows x 64 B] at +0,
//   B region [256 rows x 64 B] at +16384. Row = 32 bf16 = 64 B.
// Swizzle (64-B rows): stored byte col = logical_col ^ (((row>>1)&3)<<4).
//   ds_read lanes (fr,fq): slot = fq ^ ((fr>>1)&3) -> 8 lanes per 16-B slot
//   column, balanced across 32 banks = conflict-free-optimal.
//   Note (row>>1)&3 is invariant under +16/+64 row steps => per-lane const.
// Staging: thread t covers row sr=t>>2, byte col (t&3)*16, linear LDS dest
//   t*16; global source col inverse-swizzled. 2 async16/thread/tile.
// Register ping-pong: even tiles consume bF / preload bFn; odd tiles swap.

#define DSR(dst, base, OFF)                                     \
  asm volatile("ds_read_b128 %0, %1 offset:" OFF                \
               : "=v"(dst) : "v"(base))

#define LGKM(N)                                                  \
  asm volatile("s_waitcnt lgkmcnt(" #N ")" ::: "memory");        \
  __builtin_amdgcn_sched_barrier(0)
#define VMW(N) asm volatile("s_waitcnt vmcnt(" #N ")" ::: "memory")

#define MROW(MI, BFC)                                                          \
  do {                                                                         \
    __builtin_amdgcn_s_setprio(1);                                             \
    _Pragma("unroll") for (int ni = 0; ni < 4; ++ni)                           \
      acc[MI][ni] = __builtin_amdgcn_mfma_f32_16x16x32_bf16(                   \
          aF[MI], BFC[ni], acc[MI][ni], 0, 0, 0);                              \
    __builtin_amdgcn_s_setprio(0);                                             \
  } while (0)

// One K-tile. BFC = current B frags (in regs), BFN = next tile's (preload).
// OA*: A-read immediates for this tile's buf; DSTA/DSTB: stage dest (shorts,
// buf b^1); OB*: B-read immediates for buf b^1.
#define TILE(TT, BFC, BFN, OA0, OA1, OA2, OA3, DSTA, DSTB, OB0, OB1, OB2, OB3) \
  do {                                                                         \
    const int Tn = (TT) + 1;                                                   \
    if (Tn < NT) {                                                             \
      async16(Ablk + (Tn << 5) + aoff, dA0 + (DSTA));                          \
      async16(Bblk + (Tn << 5) + aoff, dA0 + (DSTB));                          \
    }                                                                          \
    DSR(aF[0], rA, OA0); DSR(aF[1], rA, OA1);                                  \
    DSR(aF[2], rA, OA2); DSR(aF[3], rA, OA3);                                  \
    LGKM(3);  /* drains BFC(4) + aF[0] */                                      \
    MROW(0, BFC);                                                              \
    LGKM(2);                                                                   \
    MROW(1, BFC);                                                              \
    LGKM(1);                                                                   \
    MROW(2, BFC);                                                              \
    LGKM(0);                                                                   \
    VMW(0); /* T+1 staging landed (issued at tile start, hidden by MFMA) */    \
    __builtin_amdgcn_s_barrier();                                              \
    if (Tn < NT) {                                                             \
      DSR(BFN[0], rB, OB0); DSR(BFN[1], rB, OB1);                              \
      DSR(BFN[2], rB, OB2); DSR(BFN[3], rB, OB3);                              \
    }                                                                          \
    MROW(3, BFC);                                                              \
  } while (0)

__global__ void __launch_bounds__(1024)
gemm_bt_kernel(const unsigned short* __restrict__ A,  // bf16 [M][K]
               const unsigned short* __restrict__ B,  // bf16 [N][K]
               const float* __restrict__ scale, const float* __restrict__ bias,
               float* __restrict__ C) {
  __shared__ unsigned short lds[32768];  // 64 KiB

  const int t = threadIdx.x;
  const int bid = blockIdx.x;
  const int swz = (bid & 7) * 64 + (bid >> 3);  // 512 wgs, 64/XCD (bijective)
  const int bm = swz >> 4;  // 32 M-tiles
  const int bn = swz & 15;  // 16 N-tiles
  const int brow = bm * 256, bcol = bn * 256;

  const int wid = t >> 6, lane = t & 63;
  const int wr = wid >> 2, wc = wid & 3;  // 4x4 waves, wave-tile 64x64
  const int fr = lane & 15, fq = lane >> 4;

  // staging: thread t -> row sr, 16-B chunk; inverse-swizzled global col
  const int sr = t >> 2;                       // 0..255
  const int scolb = (t & 3) * 16;              // byte col in 64-B row
  const int ssl = ((sr >> 1) & 3) << 4;
  const unsigned aoff = (unsigned)sr * 4096u + (unsigned)((scolb ^ ssl) >> 1);
  const unsigned short* Ablk = A + (size_t)brow * K_DIM;
  const unsigned short* Bblk = B + (size_t)bcol * K_DIM;
  unsigned short* dA0 = lds + t * 8;           // buf0 A dest; others by offset

  // ds_read bases (LDS byte addresses), swizzle folded per-lane
  const unsigned ldsb = (unsigned)(unsigned long long)&lds[0];
  const unsigned sl = (unsigned)(((fr >> 1) & 3) << 4);
  const unsigned rA = ldsb + (unsigned)((wr * 64 + fr) * 64) +
                      ((unsigned)(fq * 16) ^ sl);
  const unsigned rB = ldsb + (unsigned)((wc * 64 + fr) * 64) +
                      ((unsigned)(fq * 16) ^ sl);  // B region via +16384 imm

  f32x4 acc[4][4] = {};
  bf16x8 aF[4], bF[4], bFn[4];

  // ---- prologue: stage tile0 into buf0; preload bF(0) ----
  async16(Ablk + aoff, dA0);
  async16(Bblk + aoff, dA0 + 8192);
  VMW(0);
  __builtin_amdgcn_s_barrier();
  DSR(bF[0], rB, "16384"); DSR(bF[1], rB, "17408");
  DSR(bF[2], rB, "18432"); DSR(bF[3], rB, "19456");

  for (int T = 0; T < NT; T += 2) {
    // even tile: buf0 A reads; stage->buf1; preload bFn from buf1 B
    TILE(T, bF, bFn, "0", "1024", "2048", "3072", 16384, 24576,
         "49152", "50176", "51200", "52224");
    // odd tile: buf1 A reads; stage->buf0; preload bF from buf0 B
    TILE(T + 1, bFn, bF, "32768", "33792", "34816", "35840", 0, 8192,
         "16384", "17408", "18432", "19456");
  }

  // ---- epilogue: scale/bias, C/D layout col=lane&15, row=(lane>>4)*4+j ----
#pragma unroll
  for (int ni = 0; ni < 4; ++ni) {
    const int gc = bcol + wc * 64 + ni * 16 + fr;
    const float s = scale[gc];
    const float bo = bias[gc];
#pragma unroll
    for (int mi = 0; mi < 4; ++mi) {
      const int gr = brow + wr * 64 + mi * 16 + fq * 4;
#pragma unroll
      for (int j = 0; j < 4; ++j)
        C[(size_t)(gr + j) * N_DIM + gc] = acc[mi][ni][j] * s + bo;
    }
  }
}

// ---------------- naive fallback (only if ws too small) ----------------

__global__ void naive_kernel(const float* __restrict__ x, const int* __restrict__ w,
                             const float* __restrict__ sc, const float* __restrict__ bi,
                             float* __restrict__ out) {
  size_t idx = (size_t)blockIdx.x * blockDim.x + threadIdx.x;
  int m = (int)(idx >> 12);
  int n = (int)(idx & 4095);
  const float* xr = x + (size_t)m * K_DIM;
  const int* wr = w + (size_t)n * K_DIM;
  float acc = 0.f;
  for (int k = 0; k < K_DIM; ++k) acc = fmaf(xr[k], (float)wr[k], acc);
  out[idx] = acc * sc[n] + bi[n];
}

extern "C" void kernel_launch(void* const* d_in, const int* in_sizes, int n_in,
                              void* d_out, int out_size, void* d_ws, size_t ws_size,
                              hipStream_t stream) {
  const float* x = (const float*)d_in[0];
  const int* w = (const int*)d_in[1];
  const float* scale = (const float*)d_in[2];
  const float* bias = (const float*)d_in[3];
  float* out = (float*)d_out;

  const long nx = (long)M_DIM * K_DIM;
  const long nw = (long)N_DIM * K_DIM;
  const size_t need = (size_t)nx * 2 + (size_t)nw * 2;  // 96 MiB

  if (ws_size >= need) {
    unsigned short* xb = (unsigned short*)d_ws;
    unsigned short* wb = xb + nx;
    cvt_x_kernel<<<2048, 256, 0, stream>>>(x, xb, nx);
    cvt_w_kernel<<<2048, 256, 0, stream>>>(w, wb, nw);
    gemm_bt_kernel<<<512, 1024, 0, stream>>>(xb, wb, scale, bias, out);
  } else {
    naive_kernel<<<((long)M_DIM * N_DIM) / 256, 256, 0, stream>>>(x, w, scale, bias, out);
  }
}